// Round 1
// baseline (5895.811 us; speedup 1.0000x reference)
//
#include <hip/hip_runtime.h>

typedef unsigned short u16;
typedef __attribute__((ext_vector_type(4))) float f32x4;
typedef __attribute__((ext_vector_type(8))) short s16x8;

static constexpr int V = 32000;
static constexpr int C = 1024;
static constexpr int T = 1024;
static constexpr int H = 16;
static constexpr int L = 8;
static constexpr int B = 4;
static constexpr int HS = 64;
static constexpr int BT = B * T;   // 4096
static constexpr int C4 = 4 * C;   // 4096

__device__ __forceinline__ u16 f2bf(float f) {
  union { float f; unsigned u; } v; v.f = f;
  unsigned r = v.u + 0x7fffu + ((v.u >> 16) & 1u);
  return (u16)(r >> 16);
}

// ---------- block reductions (256 threads) ----------
__device__ __forceinline__ float blockReduceSum(float v) {
  __shared__ float red[4];
  int lane = threadIdx.x & 63, w = threadIdx.x >> 6;
#pragma unroll
  for (int m = 32; m >= 1; m >>= 1) v += __shfl_xor(v, m, 64);
  if (lane == 0) red[w] = v;
  __syncthreads();
  float r = red[0] + red[1] + red[2] + red[3];
  __syncthreads();
  return r;
}
__device__ __forceinline__ float blockReduceMax(float v) {
  __shared__ float redm[4];
  int lane = threadIdx.x & 63, w = threadIdx.x >> 6;
#pragma unroll
  for (int m = 32; m >= 1; m >>= 1) v = fmaxf(v, __shfl_xor(v, m, 64));
  if (lane == 0) redm[w] = v;
  __syncthreads();
  float r = fmaxf(fmaxf(redm[0], redm[1]), fmaxf(redm[2], redm[3]));
  __syncthreads();
  return r;
}

// ---------- embed: x = tok_emb[idx] + pos_emb[t]; also bf16 copy ----------
__global__ __launch_bounds__(256) void k_embed(
    const int* __restrict__ idx, const float* __restrict__ tok,
    const float* __restrict__ pos, float* __restrict__ x, u16* __restrict__ xb) {
  int bt = blockIdx.x;
  int t = bt & (T - 1);
  int row = idx[bt];
  const float* te = tok + (size_t)row * C;
  const float* pe = pos + (size_t)t * C;
  float* xo = x + (size_t)bt * C;
  u16* xbo = xb + (size_t)bt * C;
  for (int c = threadIdx.x; c < C; c += 256) {
    float v = te[c] + pe[c];
    xo[c] = v;
    xbo[c] = f2bf(v);
  }
}

// ---------- weight convert+transpose: fp32 [K,N] -> bf16 [N,K] ----------
__global__ __launch_bounds__(256) void k_transpose(
    const float* __restrict__ W, u16* __restrict__ Wt, int K, int N,
    size_t sW, size_t sWt) {
  __shared__ float tile[64][65];
  const float* Wz = W + sW * blockIdx.z;
  u16* Wtz = Wt + sWt * blockIdx.z;
  int n0 = blockIdx.x * 64, k0 = blockIdx.y * 64;
  int tc = threadIdx.x & 63, tr = threadIdx.x >> 6;
#pragma unroll
  for (int i = 0; i < 16; ++i) {
    int r = tr + i * 4;
    tile[r][tc] = Wz[(size_t)(k0 + r) * N + (n0 + tc)];
  }
  __syncthreads();
#pragma unroll
  for (int i = 0; i < 16; ++i) {
    int r = tr + i * 4;  // n-offset within tile
    Wtz[(size_t)(n0 + r) * K + (k0 + tc)] = f2bf(tile[tc][r]);
  }
}

// ---------- GEMM: C[M,N] = A[M,K](bf16) @ Bt[N,K](bf16)^T ----------
// 128x128 tile, 4 waves in 2x2, BK=32, mfma_f32_16x16x32_bf16.
template <int OUT_BF16, int RELU, int HAS_BIAS>
__global__ __launch_bounds__(256, 2) void k_gemm(
    const u16* __restrict__ A, const u16* __restrict__ Bt,
    const float* __restrict__ bias, float* __restrict__ Cf,
    u16* __restrict__ Cb, int M, int N, int K) {
  constexpr int LDT = 40;  // 32 + 8 pad shorts (80B rows, 16B aligned)
  __shared__ u16 As[128 * LDT];
  __shared__ u16 Bs[128 * LDT];
  int tid = threadIdx.x;
  int lane = tid & 63, wid = tid >> 6;
  int lm = lane & 15, lg = lane >> 4;
  int wm = wid >> 1, wn = wid & 1;
  int mb = blockIdx.y * 128, nb = blockIdx.x * 128;

  f32x4 acc[4][4];
#pragma unroll
  for (int i = 0; i < 4; ++i)
#pragma unroll
    for (int j = 0; j < 4; ++j) acc[i][j] = f32x4{0.f, 0.f, 0.f, 0.f};

  int nK = K >> 5;
  for (int kb = 0; kb < nK; ++kb) {
    __syncthreads();
#pragma unroll
    for (int it = 0; it < 2; ++it) {
      int idx = it * 256 + tid;        // 0..511
      int row = idx >> 2, q = idx & 3; // 128 rows x 4 16B-quads
      const u16* ga = A + (size_t)(mb + row) * K + kb * 32 + q * 8;
      *(s16x8*)&As[row * LDT + q * 8] = *(const s16x8*)ga;
      const u16* gb = Bt + (size_t)(nb + row) * K + kb * 32 + q * 8;
      *(s16x8*)&Bs[row * LDT + q * 8] = *(const s16x8*)gb;
    }
    __syncthreads();
    s16x8 af[4], bfr[4];
#pragma unroll
    for (int m = 0; m < 4; ++m)
      af[m] = *(const s16x8*)&As[(wm * 64 + m * 16 + lm) * LDT + lg * 8];
#pragma unroll
    for (int n = 0; n < 4; ++n)
      bfr[n] = *(const s16x8*)&Bs[(wn * 64 + n * 16 + lm) * LDT + lg * 8];
#pragma unroll
    for (int m = 0; m < 4; ++m)
#pragma unroll
      for (int n = 0; n < 4; ++n)
        acc[m][n] = __builtin_amdgcn_mfma_f32_16x16x32_bf16(af[m], bfr[n],
                                                            acc[m][n], 0, 0, 0);
  }
#pragma unroll
  for (int m = 0; m < 4; ++m) {
#pragma unroll
    for (int n = 0; n < 4; ++n) {
      int col = nb + wn * 64 + n * 16 + lm;
      float bv = HAS_BIAS ? bias[col] : 0.0f;
#pragma unroll
      for (int r = 0; r < 4; ++r) {
        int row = mb + wm * 64 + m * 16 + lg * 4 + r;
        float v = acc[m][n][r] + bv;
        if (RELU) v = v > 0.f ? v : 0.f;
        if (OUT_BF16)
          Cb[(size_t)row * N + col] = f2bf(v);
        else
          Cf[(size_t)row * N + col] = v;
      }
    }
  }
}

// ---------- fused causal attention ----------
// One block per (b, h, 16-row q-tile). Scores tile in LDS fp32, wave-parallel
// softmax, P bf16 in LDS, PV via MFMA with V staged transposed in LDS.
__global__ __launch_bounds__(256, 1) void k_attn(
    const u16* __restrict__ q, const u16* __restrict__ k,
    const u16* __restrict__ v, u16* __restrict__ o) {
  constexpr int SP = 1032;  // fp32 per S row (pad 8)
  constexpr int PP = 1032;  // u16 per P row (pad 8)
  constexpr int VP = 40;    // u16 per Vt row (32 + 8 pad)
  __shared__ float S[16 * SP];
  __shared__ u16 P[16 * PP];
  __shared__ u16 Vt[64 * VP];
  int bid = blockIdx.x;
  int qt = bid & 63, h = (bid >> 6) & 15, b = bid >> 10;
  int tid = threadIdx.x, lane = tid & 63, wid = tid >> 6;
  int lm = lane & 15, lg = lane >> 4;
  const size_t base = (size_t)b * T * C + (size_t)h * HS;

  // Q fragments (16 rows x 64)
  s16x8 qf[2];
#pragma unroll
  for (int s = 0; s < 2; ++s)
    qf[s] = *(const s16x8*)&q[base + (size_t)(qt * 16 + lm) * C + s * 32 + lg * 8];

  int ntiles = qt + 1;
  // ---- S = Q K^T (tiles split across waves) ----
  for (int nb = wid; nb < ntiles; nb += 4) {
    f32x4 acc = f32x4{0.f, 0.f, 0.f, 0.f};
#pragma unroll
    for (int s = 0; s < 2; ++s) {
      s16x8 kf =
          *(const s16x8*)&k[base + (size_t)(nb * 16 + lm) * C + s * 32 + lg * 8];
      acc = __builtin_amdgcn_mfma_f32_16x16x32_bf16(qf[s], kf, acc, 0, 0, 0);
    }
#pragma unroll
    for (int r = 0; r < 4; ++r) S[(lg * 4 + r) * SP + nb * 16 + lm] = acc[r];
  }
  __syncthreads();

  // ---- causal softmax: row r handled by 16 lanes ----
  int r = tid >> 4, ti = tid & 15;
  int qrow = qt * 16 + r;
  int nvalid = qrow + 1;
  int NkPad = (ntiles * 16 + 31) & ~31;
  const float scale = 0.125f;  // HS^-0.5
  float mx = -1e30f;
  for (int c = ti; c < nvalid; c += 16) mx = fmaxf(mx, S[r * SP + c] * scale);
#pragma unroll
  for (int m = 1; m < 16; m <<= 1) mx = fmaxf(mx, __shfl_xor(mx, m, 16));
  float sum = 0.f;
  for (int c = ti; c < nvalid; c += 16) {
    float e = __expf(S[r * SP + c] * scale - mx);
    S[r * SP + c] = e;
    sum += e;
  }
#pragma unroll
  for (int m = 1; m < 16; m <<= 1) sum += __shfl_xor(sum, m, 16);
  float inv = 1.0f / sum;
  for (int c = ti; c < nvalid; c += 16) P[r * PP + c] = f2bf(S[r * SP + c] * inv);
  for (int c = nvalid + ti; c < NkPad; c += 16) P[r * PP + c] = 0;
  __syncthreads();

  // ---- O = P V : wave w owns output cols [w*16, w*16+16) ----
  f32x4 oacc = f32x4{0.f, 0.f, 0.f, 0.f};
  int nkb = NkPad >> 5;
  for (int kb = 0; kb < nkb; ++kb) {
    __syncthreads();
    {  // stage V rows [kb*32, kb*32+32) transposed into Vt[64][VP]
      int row = tid >> 3, c8 = (tid & 7) * 8;
      s16x8 vv = *(const s16x8*)&v[base + (size_t)(kb * 32 + row) * C + c8];
#pragma unroll
      for (int j = 0; j < 8; ++j) Vt[(c8 + j) * VP + row] = (u16)vv[j];
    }
    __syncthreads();
    s16x8 pf = *(const s16x8*)&P[lm * PP + kb * 32 + lg * 8];
    s16x8 vf = *(const s16x8*)&Vt[(wid * 16 + lm) * VP + lg * 8];
    oacc = __builtin_amdgcn_mfma_f32_16x16x32_bf16(pf, vf, oacc, 0, 0, 0);
  }
#pragma unroll
  for (int r2 = 0; r2 < 4; ++r2) {
    int row = qt * 16 + lg * 4 + r2;
    int col = wid * 16 + lm;
    o[base + (size_t)row * C + col] = f2bf(oacc[r2]);
  }
}

// ---------- fused residual-add + LayerNorm ----------
template <int HAS_T>
__global__ __launch_bounds__(256) void k_ln(
    const float* __restrict__ xin, const float* __restrict__ tin,
    const float* __restrict__ g, const float* __restrict__ bsh,
    float* __restrict__ xout, u16* __restrict__ xbout) {
  int row = blockIdx.x;
  const float* xr = xin + (size_t)row * C;
  const float* trp = HAS_T ? tin + (size_t)row * C : nullptr;
  int tid = threadIdx.x;
  float vals[4];
  float s = 0.f;
#pragma unroll
  for (int i = 0; i < 4; ++i) {
    int c = tid + i * 256;
    float vv = xr[c] + (HAS_T ? trp[c] : 0.f);
    vals[i] = vv;
    s += vv;
  }
  s = blockReduceSum(s);
  float mean = s * (1.0f / C);
  float s2 = 0.f;
#pragma unroll
  for (int i = 0; i < 4; ++i) {
    float d = vals[i] - mean;
    s2 += d * d;
  }
  s2 = blockReduceSum(s2);
  float rstd = rsqrtf(s2 * (1.0f / C) + 1e-5f);
#pragma unroll
  for (int i = 0; i < 4; ++i) {
    int c = tid + i * 256;
    float y = (vals[i] - mean) * rstd * g[c] + bsh[c];
    xout[(size_t)row * C + c] = y;
    xbout[(size_t)row * C + c] = f2bf(y);
  }
}

// ---------- loss ----------
__global__ __launch_bounds__(256) void k_rowloss(
    const float* __restrict__ logits, const int* __restrict__ tgt,
    float* __restrict__ rowloss) {
  int row = blockIdx.x;
  const float* lr = logits + (size_t)row * V;
  int tid = threadIdx.x;
  float mx = -1e30f;
  for (int c = tid; c < V; c += 256) mx = fmaxf(mx, lr[c]);
  mx = blockReduceMax(mx);
  float s = 0.f;
  for (int c = tid; c < V; c += 256) s += __expf(lr[c] - mx);
  s = blockReduceSum(s);
  if (tid == 0) rowloss[row] = (logf(s) + mx) - lr[tgt[row]];
}

__global__ __launch_bounds__(256) void k_lossreduce(
    const float* __restrict__ rowloss, float* __restrict__ out) {
  __shared__ float red[256];
  int tid = threadIdx.x;
  float s = 0.f;
  for (int i = tid; i < BT; i += 256) s += rowloss[i];
  red[tid] = s;
  __syncthreads();
  for (int m = 128; m >= 1; m >>= 1) {
    if (tid < m) red[tid] += red[tid + m];
    __syncthreads();
  }
  if (tid == 0) out[0] = red[0] * (1.0f / BT);
}

// ---------------- host orchestration ----------------
extern "C" void kernel_launch(void* const* d_in, const int* in_sizes, int n_in,
                              void* d_out, int out_size, void* d_ws,
                              size_t ws_size, hipStream_t stream) {
  (void)in_sizes; (void)n_in; (void)out_size; (void)ws_size;
  const int* index = (const int*)d_in[0];
  const int* targets = (const int*)d_in[1];
  const float* tok_emb = (const float*)d_in[2];
  const float* pos_emb = (const float*)d_in[3];
  const float* wq = (const float*)d_in[4];
  const float* wk = (const float*)d_in[5];
  const float* wv = (const float*)d_in[6];
  const float* wo = (const float*)d_in[7];
  const float* bo = (const float*)d_in[8];
  const float* w1 = (const float*)d_in[9];
  const float* b1 = (const float*)d_in[10];
  const float* w2 = (const float*)d_in[11];
  const float* b2 = (const float*)d_in[12];
  const float* ln1_g = (const float*)d_in[13];
  const float* ln1_b = (const float*)d_in[14];
  const float* ln2_g = (const float*)d_in[15];
  const float* ln2_b = (const float*)d_in[16];
  const float* lnf_g = (const float*)d_in[17];
  const float* lnf_b = (const float*)d_in[18];
  const float* lm_w = (const float*)d_in[19];
  const float* lm_b = (const float*)d_in[20];

  float* logits = (float*)d_out;
  float* loss = logits + (size_t)BT * V;

  size_t off = 0;
  auto alloc = [&](size_t bytes) -> void* {
    off = (off + 255) & ~(size_t)255;
    void* p = (void*)((char*)d_ws + off);
    off += bytes;
    return p;
  };
  u16* wq_t = (u16*)alloc((size_t)L * C * C * 2);
  u16* wk_t = (u16*)alloc((size_t)L * C * C * 2);
  u16* wv_t = (u16*)alloc((size_t)L * C * C * 2);
  u16* wo_t = (u16*)alloc((size_t)L * C * C * 2);
  u16* w1_t = (u16*)alloc((size_t)L * C * C4 * 2);
  u16* w2_t = (u16*)alloc((size_t)L * C4 * C * 2);
  u16* lmw_t = (u16*)alloc((size_t)V * C * 2);
  float* x = (float*)alloc((size_t)BT * C * 4);
  float* tmp = (float*)alloc((size_t)BT * C * 4);
  u16* xb = (u16*)alloc((size_t)BT * C * 2);
  u16* qb = (u16*)alloc((size_t)BT * C * 2);
  u16* kb = (u16*)alloc((size_t)BT * C * 2);
  u16* vb = (u16*)alloc((size_t)BT * C * 2);
  u16* attb = (u16*)alloc((size_t)BT * C * 2);
  u16* hb = (u16*)alloc((size_t)BT * C4 * 2);
  float* rowloss = (float*)alloc((size_t)BT * 4);

  dim3 blk(256);
  // weight convert+transpose (every call; deterministic, no caching)
  k_transpose<<<dim3(C / 64, C / 64, L), blk, 0, stream>>>(
      wq, wq_t, C, C, (size_t)C * C, (size_t)C * C);
  k_transpose<<<dim3(C / 64, C / 64, L), blk, 0, stream>>>(
      wk, wk_t, C, C, (size_t)C * C, (size_t)C * C);
  k_transpose<<<dim3(C / 64, C / 64, L), blk, 0, stream>>>(
      wv, wv_t, C, C, (size_t)C * C, (size_t)C * C);
  k_transpose<<<dim3(C / 64, C / 64, L), blk, 0, stream>>>(
      wo, wo_t, C, C, (size_t)C * C, (size_t)C * C);
  k_transpose<<<dim3(C4 / 64, C / 64, L), blk, 0, stream>>>(
      w1, w1_t, C, C4, (size_t)C * C4, (size_t)C * C4);
  k_transpose<<<dim3(C / 64, C4 / 64, L), blk, 0, stream>>>(
      w2, w2_t, C4, C, (size_t)C4 * C, (size_t)C4 * C);
  k_transpose<<<dim3(V / 64, C / 64, 1), blk, 0, stream>>>(
      lm_w, lmw_t, C, V, 0, 0);

  k_embed<<<BT, blk, 0, stream>>>(index, tok_emb, pos_emb, x, xb);

  dim3 gCC(C / 128, BT / 128);    // N=1024
  dim3 gC4(C4 / 128, BT / 128);   // N=4096
  for (int l = 0; l < L; ++l) {
    const u16* wqt = wq_t + (size_t)l * C * C;
    const u16* wkt = wk_t + (size_t)l * C * C;
    const u16* wvt = wv_t + (size_t)l * C * C;
    const u16* wot = wo_t + (size_t)l * C * C;
    const u16* w1t = w1_t + (size_t)l * C * C4;
    const u16* w2t = w2_t + (size_t)l * C4 * C;

    k_gemm<1, 0, 0><<<gCC, blk, 0, stream>>>(xb, wqt, nullptr, nullptr, qb,
                                             BT, C, C);
    k_gemm<1, 0, 0><<<gCC, blk, 0, stream>>>(xb, wkt, nullptr, nullptr, kb,
                                             BT, C, C);
    k_gemm<1, 0, 0><<<gCC, blk, 0, stream>>>(xb, wvt, nullptr, nullptr, vb,
                                             BT, C, C);
    k_attn<<<B * H * (T / 16), blk, 0, stream>>>(qb, kb, vb, attb);
    k_gemm<0, 0, 1><<<gCC, blk, 0, stream>>>(attb, wot, bo + (size_t)l * C,
                                             tmp, nullptr, BT, C, C);
    k_ln<1><<<BT, blk, 0, stream>>>(x, tmp, ln1_g + (size_t)l * C,
                                    ln1_b + (size_t)l * C, x, xb);
    k_gemm<1, 1, 1><<<gC4, blk, 0, stream>>>(xb, w1t, b1 + (size_t)l * C4,
                                             nullptr, hb, BT, C4, C);
    k_gemm<0, 0, 1><<<gCC, blk, 0, stream>>>(hb, w2t, b2 + (size_t)l * C,
                                             tmp, nullptr, BT, C, C4);
    k_ln<1><<<BT, blk, 0, stream>>>(x, tmp, ln2_g + (size_t)l * C,
                                    ln2_b + (size_t)l * C, x, xb);
  }
  k_ln<0><<<BT, blk, 0, stream>>>(x, nullptr, lnf_g, lnf_b, x, xb);
  k_gemm<0, 0, 1><<<dim3(V / 128, BT / 128), blk, 0, stream>>>(
      xb, lmw_t, lm_b, logits, nullptr, BT, V, C);
  k_rowloss<<<BT, blk, 0, stream>>>(logits, targets, rowloss);
  k_lossreduce<<<1, blk, 0, stream>>>(rowloss, loss);
}

// Round 2
// 3344.461 us; speedup vs baseline: 1.7629x; 1.7629x over previous
//
#include <hip/hip_runtime.h>

typedef unsigned short u16;
typedef __attribute__((ext_vector_type(4))) float f32x4;
typedef __attribute__((ext_vector_type(8))) short s16x8;

static constexpr int V = 32000;
static constexpr int C = 1024;
static constexpr int T = 1024;
static constexpr int H = 16;
static constexpr int L = 8;
static constexpr int B = 4;
static constexpr int HS = 64;
static constexpr int BT = B * T;   // 4096
static constexpr int C4 = 4 * C;   // 4096
static constexpr int C3 = 3 * C;   // 3072

__device__ __forceinline__ u16 f2bf(float f) {
  union { float f; unsigned u; } v; v.f = f;
  unsigned r = v.u + 0x7fffu + ((v.u >> 16) & 1u);
  return (u16)(r >> 16);
}

__device__ __forceinline__ void gload16(const u16* g, u16* l) {
  __builtin_amdgcn_global_load_lds(
      (const __attribute__((address_space(1))) void*)g,
      (__attribute__((address_space(3))) void*)l, 16, 0, 0);
}

// ---------- block reduction (256 threads) ----------
__device__ __forceinline__ float blockReduceSum(float v) {
  __shared__ float red[4];
  int lane = threadIdx.x & 63, w = threadIdx.x >> 6;
#pragma unroll
  for (int m = 32; m >= 1; m >>= 1) v += __shfl_xor(v, m, 64);
  if (lane == 0) red[w] = v;
  __syncthreads();
  float r = red[0] + red[1] + red[2] + red[3];
  __syncthreads();
  return r;
}

// ---------- embed ----------
__global__ __launch_bounds__(256) void k_embed(
    const int* __restrict__ idx, const float* __restrict__ tok,
    const float* __restrict__ pos, float* __restrict__ x, u16* __restrict__ xb) {
  int bt = blockIdx.x;
  int t = bt & (T - 1);
  int row = idx[bt];
  const float* te = tok + (size_t)row * C;
  const float* pe = pos + (size_t)t * C;
  float* xo = x + (size_t)bt * C;
  u16* xbo = xb + (size_t)bt * C;
  for (int c = threadIdx.x; c < C; c += 256) {
    float v = te[c] + pe[c];
    xo[c] = v;
    xbo[c] = f2bf(v);
  }
}

// ---------- weight convert+transpose: fp32 [K,N] -> bf16 [N,K] ----------
__global__ __launch_bounds__(256) void k_transpose(
    const float* __restrict__ W, u16* __restrict__ Wt, int K, int N,
    size_t sW, size_t sWt) {
  __shared__ float tile[64][65];
  const float* Wz = W + sW * blockIdx.z;
  u16* Wtz = Wt + sWt * blockIdx.z;
  int n0 = blockIdx.x * 64, k0 = blockIdx.y * 64;
  int tc = threadIdx.x & 63, tr = threadIdx.x >> 6;
#pragma unroll
  for (int i = 0; i < 16; ++i) {
    int r = tr + i * 4;
    tile[r][tc] = Wz[(size_t)(k0 + r) * N + (n0 + tc)];
  }
  __syncthreads();
#pragma unroll
  for (int i = 0; i < 16; ++i) {
    int r = tr + i * 4;  // n-offset within tile
    Wtz[(size_t)(n0 + r) * K + (k0 + tc)] = f2bf(tile[tc][r]);
  }
}

// ---------- GEMM (m97 structure): C[M,N] = A[M,K](bf16) @ Bt[N,K]^T ----------
// 128x128 tile, 4 waves 2x2, BK=32, linear LDS + global_load_lds(16B),
// XCD-swizzled flat block id. Epilogue: +bias, +residual, relu, bf16/f32 out.
template <int OUT_BF16, int RELU, int HAS_BIAS, int HAS_RES>
__global__ __launch_bounds__(256, 2) void k_gemm(
    const u16* __restrict__ A, const u16* __restrict__ Bt,
    const float* __restrict__ bias, const float* __restrict__ Res,
    float* __restrict__ Cf, u16* __restrict__ Cb, int M, int N, int K) {
  __shared__ u16 As[128 * 32];
  __shared__ u16 Bs[128 * 32];
  int tid = threadIdx.x;
  int lane = tid & 63, wid = tid >> 6;
  int lm = lane & 15, lg = lane >> 4;
  int wm = wid >> 1, wn = wid & 1;

  // XCD-aware bijective swizzle of flattened block id (all grids %8==0;
  // guarded fallback otherwise).
  unsigned nbx = gridDim.x;
  unsigned nwg = nbx * gridDim.y;
  unsigned orig = blockIdx.y * nbx + blockIdx.x;
  unsigned f = ((nwg & 7u) == 0u) ? (orig & 7u) * (nwg >> 3) + (orig >> 3) : orig;
  int mb = (int)(f / nbx) * 128, nb = (int)(f % nbx) * 128;

  f32x4 acc[4][4];
#pragma unroll
  for (int i = 0; i < 4; ++i)
#pragma unroll
    for (int j = 0; j < 4; ++j) acc[i][j] = f32x4{0.f, 0.f, 0.f, 0.f};

  // staging: chunk ci = it*256 + tid; dest byte = ci*16 (linear);
  // wave-uniform LDS base = (it*4+wid)*1024 B; per-lane global source.
  int r0 = tid >> 2, q0 = tid & 3;
  int r1 = (256 + tid) >> 2, q1 = tid & 3;  // (256+tid)&3 == tid&3
  const u16* a0 = A + (size_t)(mb + r0) * K + q0 * 8;
  const u16* a1 = A + (size_t)(mb + r1) * K + q1 * 8;
  const u16* b0 = Bt + (size_t)(nb + r0) * K + q0 * 8;
  const u16* b1 = Bt + (size_t)(nb + r1) * K + q1 * 8;
  u16* lA0 = &As[wid * 512];         // bytes wid*1024
  u16* lA1 = &As[2048 + wid * 512];  // bytes 4096 + wid*1024
  u16* lB0 = &Bs[wid * 512];
  u16* lB1 = &Bs[2048 + wid * 512];

  int nK = K >> 5;
  for (int kb = 0; kb < nK; ++kb) {
    __syncthreads();
    int ko = kb * 32;
    gload16(a0 + ko, lA0);
    gload16(a1 + ko, lA1);
    gload16(b0 + ko, lB0);
    gload16(b1 + ko, lB1);
    __syncthreads();  // drains vmcnt before barrier
    s16x8 af[4], bfr[4];
#pragma unroll
    for (int m = 0; m < 4; ++m)
      af[m] = *(const s16x8*)&As[(wm * 64 + m * 16 + lm) * 32 + lg * 8];
#pragma unroll
    for (int n = 0; n < 4; ++n)
      bfr[n] = *(const s16x8*)&Bs[(wn * 64 + n * 16 + lm) * 32 + lg * 8];
#pragma unroll
    for (int m = 0; m < 4; ++m)
#pragma unroll
      for (int n = 0; n < 4; ++n)
        acc[m][n] = __builtin_amdgcn_mfma_f32_16x16x32_bf16(af[m], bfr[n],
                                                            acc[m][n], 0, 0, 0);
  }
#pragma unroll
  for (int m = 0; m < 4; ++m) {
#pragma unroll
    for (int n = 0; n < 4; ++n) {
      int col = nb + wn * 64 + n * 16 + lm;
      float bv = HAS_BIAS ? bias[col] : 0.0f;
#pragma unroll
      for (int r = 0; r < 4; ++r) {
        int row = mb + wm * 64 + m * 16 + lg * 4 + r;
        float v = acc[m][n][r] + bv;
        if (HAS_RES) v += Res[(size_t)row * N + col];
        if (RELU) v = v > 0.f ? v : 0.f;
        if (OUT_BF16)
          Cb[(size_t)row * N + col] = f2bf(v);
        else
          Cf[(size_t)row * N + col] = v;
      }
    }
  }
}

// ---------- flash attention: 64 q-rows/block, 4 waves x 16 rows ----------
// qkv: [BT][3C] bf16 fused (q | k | v per row). out: [BT][C] bf16.
__global__ __launch_bounds__(256) void k_attn(
    const u16* __restrict__ qkv, u16* __restrict__ o) {
  constexpr int KP = 72;  // K tile row stride (u16)
  constexpr int VP = 40;  // Vt row stride
  constexpr int PP = 40;  // P row stride
  __shared__ u16 Ks[32 * KP];
  __shared__ u16 Vt[64 * VP];
  __shared__ u16 Ps[4][16 * PP];
  int bid = blockIdx.x;  // qt | h | b
  int qt = bid & 15, h = (bid >> 4) & 15, b = bid >> 8;
  int tid = threadIdx.x, lane = tid & 63, wid = tid >> 6;
  int lm = lane & 15, lg = lane >> 4;
  const size_t rowbase = (size_t)b * T * C3 + (size_t)h * HS;
  int qb = qt * 64;
  int qw = qb + wid * 16;  // this wave's q-row start
  const float scale = 0.125f;

  s16x8 qf[2];
#pragma unroll
  for (int s = 0; s < 2; ++s)
    qf[s] = *(const s16x8*)&qkv[rowbase + (size_t)(qw + lm) * C3 + s * 32 + lg * 8];

  float m_[4], l_[4];
  f32x4 oacc[4];
#pragma unroll
  for (int r = 0; r < 4; ++r) { m_[r] = -3e38f; l_[r] = 0.f; }
#pragma unroll
  for (int n = 0; n < 4; ++n) oacc[n] = f32x4{0.f, 0.f, 0.f, 0.f};

  int nkt = (qb + 64) >> 5;  // k-tiles of 32 cols
  int sr = tid >> 3, sc8 = (tid & 7) * 8;  // staging coords
  for (int kt = 0; kt < nkt; ++kt) {
    __syncthreads();
    {  // stage K[32][64] row-major (padded) and V transposed Vt[64][32]
      s16x8 kv = *(const s16x8*)&qkv[rowbase + C + (size_t)(kt * 32 + sr) * C3 + sc8];
      *(s16x8*)&Ks[sr * KP + sc8] = kv;
      s16x8 vv = *(const s16x8*)&qkv[rowbase + 2 * C + (size_t)(kt * 32 + sr) * C3 + sc8];
#pragma unroll
      for (int j = 0; j < 8; ++j) Vt[(sc8 + j) * VP + sr] = (u16)vv[j];
    }
    __syncthreads();
    // S-tile [16 q-rows][32 cols] = Q K^T, two col-halves
    f32x4 s0 = f32x4{0.f, 0.f, 0.f, 0.f}, s1 = f32x4{0.f, 0.f, 0.f, 0.f};
#pragma unroll
    for (int s = 0; s < 2; ++s) {
      s16x8 k0 = *(const s16x8*)&Ks[lm * KP + s * 32 + lg * 8];
      s16x8 k1 = *(const s16x8*)&Ks[(16 + lm) * KP + s * 32 + lg * 8];
      s0 = __builtin_amdgcn_mfma_f32_16x16x32_bf16(qf[s], k0, s0, 0, 0, 0);
      s1 = __builtin_amdgcn_mfma_f32_16x16x32_bf16(qf[s], k1, s1, 0, 0, 0);
    }
    // causal mask + online softmax (C/D layout: col=lm, row=lg*4+r)
    int c0 = kt * 32 + lm, c1 = c0 + 16;
    float rmax[4];
#pragma unroll
    for (int r = 0; r < 4; ++r) {
      int row = qw + lg * 4 + r;
      float v0 = (c0 <= row) ? s0[r] * scale : -3e38f;
      float v1 = (c1 <= row) ? s1[r] * scale : -3e38f;
      s0[r] = v0; s1[r] = v1;
      rmax[r] = fmaxf(v0, v1);
    }
#pragma unroll
    for (int mm = 1; mm < 16; mm <<= 1)
#pragma unroll
      for (int r = 0; r < 4; ++r)
        rmax[r] = fmaxf(rmax[r], __shfl_xor(rmax[r], mm, 16));
    float alpha[4], rsum[4];
#pragma unroll
    for (int r = 0; r < 4; ++r) {
      float mn = fmaxf(m_[r], rmax[r]);
      alpha[r] = __expf(m_[r] - mn);
      m_[r] = mn;
      s0[r] = __expf(s0[r] - mn);
      s1[r] = __expf(s1[r] - mn);
      rsum[r] = s0[r] + s1[r];
    }
#pragma unroll
    for (int mm = 1; mm < 16; mm <<= 1)
#pragma unroll
      for (int r = 0; r < 4; ++r) rsum[r] += __shfl_xor(rsum[r], mm, 16);
#pragma unroll
    for (int r = 0; r < 4; ++r) l_[r] = l_[r] * alpha[r] + rsum[r];
#pragma unroll
    for (int n = 0; n < 4; ++n)
#pragma unroll
      for (int r = 0; r < 4; ++r) oacc[n][r] *= alpha[r];
    // P -> bf16 via per-wave LDS transpose (C/D layout -> A-frag layout)
#pragma unroll
    for (int r = 0; r < 4; ++r) {
      int pr = lg * 4 + r;
      Ps[wid][pr * PP + lm] = f2bf(s0[r]);
      Ps[wid][pr * PP + 16 + lm] = f2bf(s1[r]);
    }
    // same-wave DS ordering is FIFO; compiler inserts lgkmcnt for the read
    s16x8 pa = *(const s16x8*)&Ps[wid][lm * PP + lg * 8];
#pragma unroll
    for (int n = 0; n < 4; ++n) {
      s16x8 vf = *(const s16x8*)&Vt[(n * 16 + lm) * VP + lg * 8];
      oacc[n] = __builtin_amdgcn_mfma_f32_16x16x32_bf16(pa, vf, oacc[n], 0, 0, 0);
    }
  }
  // epilogue: normalize and store
  const size_t obase = (size_t)b * T * C + (size_t)h * HS;
  float inv[4];
#pragma unroll
  for (int r = 0; r < 4; ++r) inv[r] = 1.0f / l_[r];
#pragma unroll
  for (int n = 0; n < 4; ++n)
#pragma unroll
    for (int r = 0; r < 4; ++r)
      o[obase + (size_t)(qw + lg * 4 + r) * C + n * 16 + lm] =
          f2bf(oacc[n][r] * inv[r]);
}

// ---------- LayerNorm (single input; residual pre-added by GEMM) ----------
__global__ __launch_bounds__(256) void k_ln(
    const float* __restrict__ in, const float* __restrict__ g,
    const float* __restrict__ bsh, float* __restrict__ xout,
    u16* __restrict__ xbout) {
  int row = blockIdx.x;
  const float* xr = in + (size_t)row * C;
  int tid = threadIdx.x;
  float vals[4];
  float s = 0.f;
#pragma unroll
  for (int i = 0; i < 4; ++i) {
    float vv = xr[tid + i * 256];
    vals[i] = vv;
    s += vv;
  }
  s = blockReduceSum(s);
  float mean = s * (1.0f / C);
  float s2 = 0.f;
#pragma unroll
  for (int i = 0; i < 4; ++i) {
    float d = vals[i] - mean;
    s2 += d * d;
  }
  s2 = blockReduceSum(s2);
  float rstd = rsqrtf(s2 * (1.0f / C) + 1e-5f);
#pragma unroll
  for (int i = 0; i < 4; ++i) {
    int c = tid + i * 256;
    float y = (vals[i] - mean) * rstd * g[c] + bsh[c];
    xout[(size_t)row * C + c] = y;
    xbout[(size_t)row * C + c] = f2bf(y);
  }
}

// ---------- loss: single-pass online logsumexp per row ----------
__global__ __launch_bounds__(256) void k_rowloss(
    const float* __restrict__ logits, const int* __restrict__ tgt,
    float* __restrict__ rowloss) {
  int row = blockIdx.x;
  const float* lr = logits + (size_t)row * V;
  const f32x4* lr4 = (const f32x4*)lr;
  int tid = threadIdx.x;
  float m = -3e38f, s = 0.f;
  for (int i = tid; i < V / 4; i += 256) {
    f32x4 v = lr4[i];
#pragma unroll
    for (int j = 0; j < 4; ++j) {
      float x = v[j];
      if (x > m) {
        s = s * __expf(m - x) + 1.f;
        m = x;
      } else {
        s += __expf(x - m);
      }
    }
  }
#pragma unroll
  for (int d = 1; d < 64; d <<= 1) {
    float mo = __shfl_xor(m, d, 64), so = __shfl_xor(s, d, 64);
    float mn = fmaxf(m, mo);
    s = s * __expf(m - mn) + so * __expf(mo - mn);
    m = mn;
  }
  __shared__ float sm[4], ss[4];
  int w = tid >> 6;
  if ((tid & 63) == 0) { sm[w] = m; ss[w] = s; }
  __syncthreads();
  if (tid == 0) {
    float M = fmaxf(fmaxf(sm[0], sm[1]), fmaxf(sm[2], sm[3]));
    float S = ss[0] * __expf(sm[0] - M) + ss[1] * __expf(sm[1] - M) +
              ss[2] * __expf(sm[2] - M) + ss[3] * __expf(sm[3] - M);
    rowloss[row] = (M + logf(S)) - lr[tgt[row]];
  }
}

__global__ __launch_bounds__(256) void k_lossreduce(
    const float* __restrict__ rowloss, float* __restrict__ out) {
  __shared__ float red[256];
  int tid = threadIdx.x;
  float s = 0.f;
  for (int i = tid; i < BT; i += 256) s += rowloss[i];
  red[tid] = s;
  __syncthreads();
  for (int m = 128; m >= 1; m >>= 1) {
    if (tid < m) red[tid] += red[tid + m];
    __syncthreads();
  }
  if (tid == 0) out[0] = red[0] * (1.0f / BT);
}

// ---------------- host orchestration ----------------
extern "C" void kernel_launch(void* const* d_in, const int* in_sizes, int n_in,
                              void* d_out, int out_size, void* d_ws,
                              size_t ws_size, hipStream_t stream) {
  (void)in_sizes; (void)n_in; (void)out_size; (void)ws_size;
  const int* index = (const int*)d_in[0];
  const int* targets = (const int*)d_in[1];
  const float* tok_emb = (const float*)d_in[2];
  const float* pos_emb = (const float*)d_in[3];
  const float* wq = (const float*)d_in[4];
  const float* wk = (const float*)d_in[5];
  const float* wv = (const float*)d_in[6];
  const float* wo = (const float*)d_in[7];
  const float* bo = (const float*)d_in[8];
  const float* w1 = (const float*)d_in[9];
  const float* b1 = (const float*)d_in[10];
  const float* w2 = (const float*)d_in[11];
  const float* b2 = (const float*)d_in[12];
  const float* ln1_g = (const float*)d_in[13];
  const float* ln1_b = (const float*)d_in[14];
  const float* ln2_g = (const float*)d_in[15];
  const float* ln2_b = (const float*)d_in[16];
  const float* lnf_g = (const float*)d_in[17];
  const float* lnf_b = (const float*)d_in[18];
  const float* lm_w = (const float*)d_in[19];
  const float* lm_b = (const float*)d_in[20];

  float* logits = (float*)d_out;
  float* loss = logits + (size_t)BT * V;

  size_t off = 0;
  auto alloc = [&](size_t bytes) -> void* {
    off = (off + 255) & ~(size_t)255;
    void* p = (void*)((char*)d_ws + off);
    off += bytes;
    return p;
  };
  u16* wqkv_t = (u16*)alloc((size_t)L * C3 * C * 2);  // [L][3C][C]
  u16* wo_t = (u16*)alloc((size_t)L * C * C * 2);
  u16* w1_t = (u16*)alloc((size_t)L * C * C4 * 2);
  u16* w2_t = (u16*)alloc((size_t)L * C4 * C * 2);
  u16* lmw_t = (u16*)alloc((size_t)V * C * 2);
  float* x = (float*)alloc((size_t)BT * C * 4);
  float* tmp = (float*)alloc((size_t)BT * C * 4);
  u16* xb = (u16*)alloc((size_t)BT * C * 2);
  u16* qkvb = (u16*)alloc((size_t)BT * C3 * 2);
  u16* attb = (u16*)alloc((size_t)BT * C * 2);
  u16* hb = (u16*)alloc((size_t)BT * C4 * 2);
  float* rowloss = (float*)alloc((size_t)BT * 4);

  dim3 blk(256);
  // weight convert+transpose; q/k/v interleave into [3C][C] per layer
  k_transpose<<<dim3(C / 64, C / 64, L), blk, 0, stream>>>(
      wq, wqkv_t, C, C, (size_t)C * C, (size_t)C3 * C);
  k_transpose<<<dim3(C / 64, C / 64, L), blk, 0, stream>>>(
      wk, wqkv_t + (size_t)C * C, C, C, (size_t)C * C, (size_t)C3 * C);
  k_transpose<<<dim3(C / 64, C / 64, L), blk, 0, stream>>>(
      wv, wqkv_t + (size_t)2 * C * C, C, C, (size_t)C * C, (size_t)C3 * C);
  k_transpose<<<dim3(C / 64, C / 64, L), blk, 0, stream>>>(
      wo, wo_t, C, C, (size_t)C * C, (size_t)C * C);
  k_transpose<<<dim3(C4 / 64, C / 64, L), blk, 0, stream>>>(
      w1, w1_t, C, C4, (size_t)C * C4, (size_t)C * C4);
  k_transpose<<<dim3(C / 64, C4 / 64, L), blk, 0, stream>>>(
      w2, w2_t, C4, C, (size_t)C4 * C, (size_t)C4 * C);
  k_transpose<<<dim3(V / 64, C / 64, 1), blk, 0, stream>>>(
      lm_w, lmw_t, C, V, 0, 0);

  k_embed<<<BT, blk, 0, stream>>>(index, tok_emb, pos_emb, x, xb);

  dim3 gQKV(C3 / 128, BT / 128);
  dim3 gCC(C / 128, BT / 128);
  dim3 gC4(C4 / 128, BT / 128);
  for (int l = 0; l < L; ++l) {
    const u16* wqkvt = wqkv_t + (size_t)l * C3 * C;
    const u16* wot = wo_t + (size_t)l * C * C;
    const u16* w1t = w1_t + (size_t)l * C * C4;
    const u16* w2t = w2_t + (size_t)l * C4 * C;

    k_gemm<1, 0, 0, 0><<<gQKV, blk, 0, stream>>>(
        xb, wqkvt, nullptr, nullptr, nullptr, qkvb, BT, C3, C);
    k_attn<<<B * H * (T / 64), blk, 0, stream>>>(qkvb, attb);
    k_gemm<0, 0, 1, 1><<<gCC, blk, 0, stream>>>(
        attb, wot, bo + (size_t)l * C, x, tmp, nullptr, BT, C, C);
    k_ln<<<BT, blk, 0, stream>>>(tmp, ln1_g + (size_t)l * C,
                                 ln1_b + (size_t)l * C, x, xb);
    k_gemm<1, 1, 1, 0><<<gC4, blk, 0, stream>>>(
        xb, w1t, b1 + (size_t)l * C4, nullptr, nullptr, hb, BT, C4, C);
    k_gemm<0, 0, 1, 1><<<gCC, blk, 0, stream>>>(
        hb, w2t, b2 + (size_t)l * C, x, tmp, nullptr, BT, C, C4);
    k_ln<<<BT, blk, 0, stream>>>(tmp, ln2_g + (size_t)l * C,
                                 ln2_b + (size_t)l * C, x, xb);
  }
  k_ln<<<BT, blk, 0, stream>>>(x, lnf_g, lnf_b, x, xb);
  k_gemm<0, 0, 1, 0><<<dim3(V / 128, BT / 128), blk, 0, stream>>>(
      xb, lmw_t, lm_b, nullptr, logits, nullptr, BT, V, C);
  k_rowloss<<<BT, blk, 0, stream>>>(logits, targets, rowloss);
  k_lossreduce<<<1, blk, 0, stream>>>(rowloss, loss);
}